// Round 1
// baseline (4731.088 us; speedup 1.0000x reference)
//
#include <hip/hip_runtime.h>
#include <math.h>

#define NSLOTS 32
#define DIM    1024
#define NTOK   2048
#define NROWS  32768

#define MOM      0.95f
#define OMM      0.05f
#define MOM2     0.9025f   // 0.95^2
#define MOMOMM2  0.095f    // 2*0.95*0.05
#define OMM2     0.0025f   // 0.05^2
#define INV_TEMP (1.0f/0.35f)
#define COS_EPS  1e-8f
#define NORM_EPS 1e-12f

__device__ __forceinline__ float reduce_all(float v) {
    v += __shfl_xor(v, 32, 64);
    v += __shfl_xor(v, 16, 64);
    v += __shfl_xor(v, 8, 64);
    v += __shfl_xor(v, 4, 64);
    v += __shfl_xor(v, 2, 64);
    v += __shfl_xor(v, 1, 64);
    return v;
}

// 8-value halving butterfly over 64 lanes.
// Returns full-wave sum of value s where s = (lane>>3)&7; all 8 lanes of a
// group share the result.
__device__ __forceinline__ float reduce8(const float v[8], int lane) {
    const bool b5 = (lane & 32) != 0;
    const bool b4 = (lane & 16) != 0;
    const bool b3 = (lane & 8) != 0;
    float t[4];
#pragma unroll
    for (int k = 0; k < 4; ++k) {
        float send = b5 ? v[k] : v[k + 4];
        float recv = __shfl_xor(send, 32, 64);
        t[k] = (b5 ? v[k + 4] : v[k]) + recv;
    }
    float u[2];
#pragma unroll
    for (int k = 0; k < 2; ++k) {
        float send = b4 ? t[k] : t[k + 2];
        float recv = __shfl_xor(send, 16, 64);
        u[k] = (b4 ? t[k + 2] : t[k]) + recv;
    }
    float send = b3 ? u[0] : u[1];
    float recv = __shfl_xor(send, 8, 64);
    float r = (b3 ? u[1] : u[0]) + recv;
    r += __shfl_xor(r, 4, 64);
    r += __shfl_xor(r, 2, 64);
    r += __shfl_xor(r, 1, 64);
    return r;
}

// 4-value variant; result for r = (lane>>4)&3, shared by all 16 lanes of group.
__device__ __forceinline__ float reduce4(const float v[4], int lane) {
    const bool b5 = (lane & 32) != 0;
    const bool b4 = (lane & 16) != 0;
    float t[2];
#pragma unroll
    for (int k = 0; k < 2; ++k) {
        float send = b5 ? v[k] : v[k + 2];
        float recv = __shfl_xor(send, 32, 64);
        t[k] = (b5 ? v[k + 2] : v[k]) + recv;
    }
    float send = b4 ? t[0] : t[1];
    float recv = __shfl_xor(send, 16, 64);
    float r = (b4 ? t[1] : t[0]) + recv;
    r += __shfl_xor(r, 8, 64);
    r += __shfl_xor(r, 4, 64);
    r += __shfl_xor(r, 2, 64);
    r += __shfl_xor(r, 1, 64);
    return r;
}

#define UPDATE_SLOT(i) { _Pragma("unroll") \
    for (int k = 0; k < 16; ++k) sreg[i][k] = MOM * sreg[i][k] + OMM * tv[k]; }

// ---------------------------------------------------------------------------
// Sequential routing scan: 1 block, 256 threads (4 waves, 8 slots per wave).
// Lane j handles dims d(j,q,k) = 256*q + 4*j + k (q,k in 0..3) of each of its
// wave's 8 slots; slots live entirely in VGPRs (128 regs/lane).
// ---------------------------------------------------------------------------
__global__ __launch_bounds__(256, 1) void scan_kernel(
    const float* __restrict__ wb,        // [2048,1024]
    const float* __restrict__ slots_in,  // [32,1024]
    const float* __restrict__ usage_in,  // [32]
    float* __restrict__ sn_out,          // [32*1024] normalized slots
    float* __restrict__ ns_out)          // [32] slot norms
{
    const int tid = threadIdx.x;
    const int w = tid >> 6;
    const int j = tid & 63;

    __shared__ __align__(16) float tokL[DIM];
    __shared__ float ntp[4];
    __shared__ float simsL[NSLOTS];

    float sreg[8][16];
#pragma unroll
    for (int i = 0; i < 8; ++i) {
        const int s = 8 * w + i;
#pragma unroll
        for (int q = 0; q < 4; ++q) {
            float4 v = *(const float4*)&slots_in[s * DIM + 256 * q + 4 * j];
            sreg[i][4*q+0] = v.x; sreg[i][4*q+1] = v.y;
            sreg[i][4*q+2] = v.z; sreg[i][4*q+3] = v.w;
        }
    }
    // distributed squared norms: lane's ssd is for slot 8*w + ((j>>3)&7)
    float ssd;
    {
        float v[8];
#pragma unroll
        for (int i = 0; i < 8; ++i) {
            float a = 0.0f;
#pragma unroll
            for (int k = 0; k < 16; ++k) a = fmaf(sreg[i][k], sreg[i][k], a);
            v[i] = a;
        }
        ssd = reduce8(v, j);
    }
    unsigned emptyMask = 0;
    for (int s = 0; s < NSLOTS; ++s)
        if (usage_in[s] == 0.0f) emptyMask |= (1u << s);

    // depth-2 token prefetch
    float4 gA = *(const float4*)&wb[0 * DIM + 4 * tid];
    float4 gB = *(const float4*)&wb[1 * DIM + 4 * tid];

#pragma unroll 1
    for (int t = 0; t < NTOK; ++t) {
        const float4 gc = gA;
        gA = gB;
        if (t + 2 < NTOK) gB = *(const float4*)&wb[(t + 2) * DIM + 4 * tid];

        *(float4*)&tokL[4 * tid] = gc;
        float s2 = gc.x*gc.x + gc.y*gc.y + gc.z*gc.z + gc.w*gc.w;
        s2 = reduce_all(s2);
        if (j == 0) ntp[w] = s2;
        __syncthreads();   // B1: token + norm partials visible

        const float nt2 = ntp[0] + ntp[1] + ntp[2] + ntp[3];
        const float invnt = 1.0f / fmaxf(sqrtf(nt2), COS_EPS);

        float tv[16];
#pragma unroll
        for (int q = 0; q < 4; ++q) {
            float4 tq = *(const float4*)&tokL[256 * q + 4 * j];
            tv[4*q+0] = tq.x; tv[4*q+1] = tq.y; tv[4*q+2] = tq.z; tv[4*q+3] = tq.w;
        }
        float vv[8];
#pragma unroll
        for (int i = 0; i < 8; ++i) {
            float a = 0.0f;
#pragma unroll
            for (int k = 0; k < 16; ++k) a = fmaf(sreg[i][k], tv[k], a);
            vv[i] = a;
        }
        const float dotd = reduce8(vv, j);   // raw dot(slot, token) for lane's group slot
        const float invd = 1.0f / fmaxf(sqrtf(ssd), COS_EPS);
        if ((j & 7) == 0) simsL[8 * w + (j >> 3)] = dotd * invd * invnt;
        __syncthreads();   // B2: sims visible

        int idx;
        if (emptyMask) {                      // uniform branch
            idx = (int)__builtin_ctz(emptyMask);
            emptyMask &= ~(1u << idx);
        } else {
            // first-max argmax over 32 sims (duplicated in lanes 32..63)
            float bv = simsL[j & 31];
            int bi = j & 31;
#pragma unroll
            for (int m = 1; m < 64; m <<= 1) {
                float ov = __shfl_xor(bv, m, 64);
                int   oi = __shfl_xor(bi, m, 64);
                if (ov > bv || (ov == bv && oi < bi)) { bv = ov; bi = oi; }
            }
            idx = bi;
        }

        if ((idx >> 3) == w) {                // owning wave updates its slot
            switch (idx & 7) {
                case 0: UPDATE_SLOT(0); break;
                case 1: UPDATE_SLOT(1); break;
                case 2: UPDATE_SLOT(2); break;
                case 3: UPDATE_SLOT(3); break;
                case 4: UPDATE_SLOT(4); break;
                case 5: UPDATE_SLOT(5); break;
                case 6: UPDATE_SLOT(6); break;
                case 7: UPDATE_SLOT(7); break;
            }
            if ((j >> 3) == (idx & 7))
                // ||0.95 a + 0.05 b||^2 = 0.9025||a||^2 + 0.095 a.b + 0.0025||b||^2
                ssd = MOM2 * ssd + MOMOMM2 * dotd + OMM2 * nt2;
        }
    }

    // epilogue: write normalized slots + norms
    const float nsv = sqrtf(ssd);
    if ((j & 7) == 0) ns_out[8 * w + (j >> 3)] = nsv;
#pragma unroll
    for (int i = 0; i < 8; ++i) {
        const float ns_i = __shfl(nsv, i << 3, 64);
        const float inv_i = 1.0f / fmaxf(ns_i, NORM_EPS);
        const int s = 8 * w + i;
#pragma unroll
        for (int q = 0; q < 4; ++q) {
            float4 o;
            o.x = sreg[i][4*q+0] * inv_i;
            o.y = sreg[i][4*q+1] * inv_i;
            o.z = sreg[i][4*q+2] * inv_i;
            o.w = sreg[i][4*q+3] * inv_i;
            *(float4*)&sn_out[s * DIM + 256 * q + 4 * j] = o;
        }
    }
}

// ---------------------------------------------------------------------------
// Retrieve: 1024 blocks x 512 threads; each wave handles 4 rows.
// Normalized slots staged through a 32 KB LDS buffer in 8-slot passes.
// ---------------------------------------------------------------------------
__global__ __launch_bounds__(512, 2) void retrieve_kernel(
    const float* __restrict__ x,
    const float* __restrict__ sn_g,
    const float* __restrict__ ns_g,
    float* __restrict__ out)
{
    __shared__ __align__(16) float snL[8 * DIM];          // 32 KB
    __shared__ float nsL[NSLOTS];
    __shared__ __align__(16) float scL[8 * 4 * NSLOTS];   // [wave][row][slot]

    const int tid = threadIdx.x;
    const int w = tid >> 6;
    const int j = tid & 63;

    if (tid < NSLOTS) nsL[tid] = ns_g[tid];

    const int rowbase = (blockIdx.x * 8 + w) * 4;

    float xv[4][16];
#pragma unroll
    for (int r = 0; r < 4; ++r) {
        const float* xr = &x[(long)(rowbase + r) * DIM];
#pragma unroll
        for (int q = 0; q < 4; ++q) {
            float4 v = *(const float4*)&xr[256 * q + 4 * j];
            xv[r][4*q+0] = v.x; xv[r][4*q+1] = v.y;
            xv[r][4*q+2] = v.z; xv[r][4*q+3] = v.w;
        }
    }
    float mul[4];
#pragma unroll
    for (int r = 0; r < 4; ++r) {
        float a = 0.0f;
#pragma unroll
        for (int k = 0; k < 16; ++k) a = fmaf(xv[r][k], xv[r][k], a);
        a = reduce_all(a);
        mul[r] = (1.0f / fmaxf(sqrtf(a), NORM_EPS)) * INV_TEMP;
    }

    // ---- scores: raw dots into scL, 8 slots per LDS pass
#pragma unroll 1
    for (int h = 0; h < 4; ++h) {
        if (h) __syncthreads();
        for (int i = tid; i < 8 * DIM / 4; i += 512)
            *(float4*)&snL[4 * i] = *(const float4*)&sn_g[h * 8 * DIM + 4 * i];
        __syncthreads();
#pragma unroll 1
        for (int si = 0; si < 8; ++si) {
            const int s = 8 * h + si;
            float snv[16];
#pragma unroll
            for (int q = 0; q < 4; ++q) {
                float4 v = *(const float4*)&snL[si * DIM + 256 * q + 4 * j];
                snv[4*q+0]=v.x; snv[4*q+1]=v.y; snv[4*q+2]=v.z; snv[4*q+3]=v.w;
            }
            float p[4];
#pragma unroll
            for (int r = 0; r < 4; ++r) {
                float a = 0.0f;
#pragma unroll
                for (int k = 0; k < 16; ++k) a = fmaf(xv[r][k], snv[k], a);
                p[r] = a;
            }
            float d = reduce4(p, j);
            if ((j & 15) == 0) scL[w * 128 + (j >> 4) * 32 + s] = d;
        }
    }

    // ---- softmax (each lane redundantly handles row r = j&3), then write
    //      weight*slot_norm back into scL
    {
        const int r = j & 3;
        const float mulr = (r == 0) ? mul[0] : (r == 1) ? mul[1]
                         : (r == 2) ? mul[2] : mul[3];
        float sc[32];
#pragma unroll
        for (int s4 = 0; s4 < 8; ++s4) {
            float4 v = *(const float4*)&scL[w * 128 + r * 32 + 4 * s4];
            sc[4*s4+0]=v.x; sc[4*s4+1]=v.y; sc[4*s4+2]=v.z; sc[4*s4+3]=v.w;
        }
        float m = -INFINITY;
#pragma unroll
        for (int s = 0; s < 32; ++s) { sc[s] *= mulr; m = fmaxf(m, sc[s]); }
        float sum = 0.0f;
#pragma unroll
        for (int s = 0; s < 32; ++s) { sc[s] = expf(sc[s] - m); sum += sc[s]; }
        const float isum = 1.0f / sum;
        if (j < 4) {   // lanes 0..3 write the 32 weights for their row
#pragma unroll
            for (int s4 = 0; s4 < 8; ++s4) {
                float4 o;
                o.x = sc[4*s4+0] * isum * nsL[4*s4+0];
                o.y = sc[4*s4+1] * isum * nsL[4*s4+1];
                o.z = sc[4*s4+2] * isum * nsL[4*s4+2];
                o.w = sc[4*s4+3] * isum * nsL[4*s4+3];
                *(float4*)&scL[w * 128 + j * 32 + 4 * s4] = o;
            }
        }
    }

    // ---- out = sum_s (w[s]*ns[s]) * sn[s][d]; walk LDS passes back down
    float acc[4][16];
#pragma unroll
    for (int r = 0; r < 4; ++r)
#pragma unroll
        for (int k = 0; k < 16; ++k) acc[r][k] = 0.0f;

#pragma unroll 1
    for (int h = 3; h >= 0; --h) {
        if (h != 3) {
            __syncthreads();
            for (int i = tid; i < 8 * DIM / 4; i += 512)
                *(float4*)&snL[4 * i] = *(const float4*)&sn_g[h * 8 * DIM + 4 * i];
            __syncthreads();
        }
#pragma unroll 1
        for (int si = 0; si < 8; ++si) {
            const int s = 8 * h + si;
            float snv[16];
#pragma unroll
            for (int q = 0; q < 4; ++q) {
                float4 v = *(const float4*)&snL[si * DIM + 256 * q + 4 * j];
                snv[4*q+0]=v.x; snv[4*q+1]=v.y; snv[4*q+2]=v.z; snv[4*q+3]=v.w;
            }
#pragma unroll
            for (int r = 0; r < 4; ++r) {
                const float ww = scL[w * 128 + r * 32 + s];
#pragma unroll
                for (int k = 0; k < 16; ++k) acc[r][k] = fmaf(ww, snv[k], acc[r][k]);
            }
        }
    }

#pragma unroll
    for (int r = 0; r < 4; ++r) {
        float* orow = &out[(long)(rowbase + r) * DIM];
#pragma unroll
        for (int q = 0; q < 4; ++q) {
            float4 o;
            o.x = acc[r][4*q+0]; o.y = acc[r][4*q+1];
            o.z = acc[r][4*q+2]; o.w = acc[r][4*q+3];
            *(float4*)&orow[256 * q + 4 * j] = o;
        }
    }
}

extern "C" void kernel_launch(void* const* d_in, const int* in_sizes, int n_in,
                              void* d_out, int out_size, void* d_ws, size_t ws_size,
                              hipStream_t stream) {
    const float* x  = (const float*)d_in[0];   // [4,8192,1024]
    const float* wb = (const float*)d_in[1];   // [2048,1024]
    const float* sl = (const float*)d_in[2];   // [32,1024]
    const float* us = (const float*)d_in[3];   // [32]
    float* out = (float*)d_out;
    float* sn = (float*)d_ws;                  // 32*1024 floats
    float* ns = sn + NSLOTS * DIM;             // 32 floats

    scan_kernel<<<dim3(1), dim3(256), 0, stream>>>(wb, sl, us, sn, ns);
    retrieve_kernel<<<dim3(NROWS / 32), dim3(512), 0, stream>>>(x, sn, ns, out);
}